// Round 1
// baseline (268.319 us; speedup 1.0000x reference)
//
#include <hip/hip_runtime.h>

#define B_   2
#define SQ_  2048
#define SK_  512
#define HID_ 1024
#define NH_  16
#define HD_  64

typedef __bf16 bf16x8 __attribute__((ext_vector_type(8)));
typedef float  f32x4  __attribute__((ext_vector_type(4)));

__device__ __forceinline__ unsigned short f2bf(float f) {
    unsigned u = __builtin_bit_cast(unsigned, f);
    u += 0x7fffu + ((u >> 16) & 1u);   // round-to-nearest-even
    return (unsigned short)(u >> 16);
}

// async global->LDS, 16B per lane, lands at lds_base + lane*16
__device__ __forceinline__ void gll16(const unsigned short* g, unsigned short* l) {
    __builtin_amdgcn_global_load_lds(
        (const __attribute__((address_space(1))) unsigned int*)(const void*)g,
        (__attribute__((address_space(3))) unsigned int*)(void*)l,
        16, 0, 0);
}

// ---------------- fused fp32 -> bf16 conversion (all 5 tensors) ----------------
__global__ __launch_bounds__(256) void cvt_all(const float* __restrict__ hs,
                                               const float* __restrict__ enc,
                                               const float* __restrict__ wq,
                                               const float* __restrict__ wk,
                                               const float* __restrict__ wv,
                                               unsigned short* __restrict__ hb,
                                               unsigned short* __restrict__ eb,
                                               unsigned short* __restrict__ wqb,
                                               unsigned short* __restrict__ wkb,
                                               unsigned short* __restrict__ wvb) {
    size_t i = ((size_t)blockIdx.x * 256 + threadIdx.x) * 4;
    const float* s; unsigned short* d; size_t off;
    if (i < 4194304)      { s = hs;  d = hb;  off = i; }
    else if (i < 5242880) { s = enc; d = eb;  off = i - 4194304; }
    else if (i < 6291456) { s = wq;  d = wqb; off = i - 5242880; }
    else if (i < 7340032) { s = wk;  d = wkb; off = i - 6291456; }
    else                  { s = wv;  d = wvb; off = i - 7340032; }
    float4 v = *reinterpret_cast<const float4*>(s + off);
    ushort4 o;
    o.x = f2bf(v.x); o.y = f2bf(v.y); o.z = f2bf(v.z); o.w = f2bf(v.w);
    *reinterpret_cast<ushort4*>(d + off) = o;
}

// ---------------- fused QKV NT GEMM ----------------
// m97-structure: 128x128 tiles, BK=32, global_load_lds staging, XOR-swizzled
// 64B-row chunks, 4 waves in 2x2, each wave owns a 64x64 sub-tile (4x4 frags).
// grid 384 = 48 m-superblocks x 8 n-blocks, bijective XCD swizzle (384%8==0).
// ms 0..31:  Q (A=hb, W=wq) -> qo [b,h,s,d]
// ms 32..39: K (A=eb, W=wk) -> ko [b,h,s,d]
// ms 40..47: V (A=eb, W=wv) -> vo [b,h,d,s]  (pre-transposed for attention)
__global__ __launch_bounds__(256, 3) void gemm_qkv(const unsigned short* __restrict__ hb,
                                                   const unsigned short* __restrict__ eb,
                                                   const unsigned short* __restrict__ wq,
                                                   const unsigned short* __restrict__ wk,
                                                   const unsigned short* __restrict__ wv,
                                                   unsigned short* __restrict__ qo,
                                                   unsigned short* __restrict__ ko,
                                                   unsigned short* __restrict__ vo) {
    __shared__ unsigned short as[128 * 32];   // [row][32 k], rows of 64B, swizzled chunks
    __shared__ unsigned short bs[128 * 32];

    int bid = blockIdx.x;
    bid = (bid & 7) * 48 + (bid >> 3);        // XCD swizzle: XCD k gets contiguous ms range
    int nb = bid & 7, ms = bid >> 3;
    const unsigned short* Ab; const unsigned short* Wb;
    int mrow, mode;
    if (ms < 32)      { mode = 0; Ab = hb; Wb = wq; mrow = ms * 128; }
    else if (ms < 40) { mode = 1; Ab = eb; Wb = wk; mrow = (ms - 32) * 128; }
    else              { mode = 2; Ab = eb; Wb = wv; mrow = (ms - 40) * 128; }
    int n0 = nb * 128;

    int tid = threadIdx.x, lane = tid & 63, w = tid >> 6;
    int quad = lane >> 4, lc = lane & 15;
    int wr = w >> 1, wc = w & 1;              // wave position in 2x2

    // loader lane mapping: row-in-16 = lane>>2, slot = lane&3,
    // fetched logical chunk = slot ^ ((row>>1)&3); wave w stages rows [32w,32w+32)
    int lrow = lane >> 2;
    int chA  = (lane & 3) ^ ((lane >> 3) & 3);
    const unsigned short* agp0 = Ab + (size_t)(mrow + w * 32 + lrow) * 1024 + chA * 8;
    const unsigned short* agp1 = agp0 + (size_t)16 * 1024;
    const unsigned short* bgp0 = Wb + (size_t)(n0 + w * 32 + lrow) * 1024 + chA * 8;
    const unsigned short* bgp1 = bgp0 + (size_t)16 * 1024;
    unsigned short* asl0 = &as[(w * 32) * 32];
    unsigned short* asl1 = &as[(w * 32 + 16) * 32];
    unsigned short* bsl0 = &bs[(w * 32) * 32];
    unsigned short* bsl1 = &bs[(w * 32 + 16) * 32];

    f32x4 zero4 = {0.f, 0.f, 0.f, 0.f};
    f32x4 acc[4][4];
#pragma unroll
    for (int i = 0; i < 4; i++)
#pragma unroll
        for (int j = 0; j < 4; j++) acc[i][j] = zero4;

    int rsw = (lc >> 1) & 3;   // reader swizzle key = (row&15)>>1 & 3
    for (int k0 = 0; k0 < 1024; k0 += 32) {
        gll16(agp0 + k0, asl0);
        gll16(agp1 + k0, asl1);
        gll16(bgp0 + k0, bsl0);
        gll16(bgp1 + k0, bsl1);
        __syncthreads();
        bf16x8 af[4], bfr[4];
#pragma unroll
        for (int mt = 0; mt < 4; mt++)
            af[mt] = *reinterpret_cast<const bf16x8*>(
                &as[(wr * 64 + mt * 16 + lc) * 32 + (quad ^ rsw) * 8]);
#pragma unroll
        for (int nt = 0; nt < 4; nt++)
            bfr[nt] = *reinterpret_cast<const bf16x8*>(
                &bs[(wc * 64 + nt * 16 + lc) * 32 + (quad ^ rsw) * 8]);
#pragma unroll
        for (int mt = 0; mt < 4; mt++)
#pragma unroll
            for (int nt = 0; nt < 4; nt++)
                acc[mt][nt] = __builtin_amdgcn_mfma_f32_16x16x32_bf16(af[mt], bfr[nt], acc[mt][nt], 0, 0, 0);
        __syncthreads();
    }

#pragma unroll
    for (int mt = 0; mt < 4; mt++) {
#pragma unroll
        for (int nt = 0; nt < 4; nt++) {
            int n = n0 + wc * 64 + nt * 16 + lc;
            int h = n >> 6, d = n & 63;
#pragma unroll
            for (int r = 0; r < 4; r++) {
                int M = mrow + wr * 64 + mt * 16 + quad * 4 + r;
                unsigned short val = f2bf(acc[mt][nt][r]);
                if (mode == 0) {
                    int b = M >> 11, s = M & 2047;
                    qo[(((size_t)(b * NH_ + h)) * SQ_ + s) * HD_ + d] = val;
                } else if (mode == 1) {
                    int b = M >> 9, s = M & 511;
                    ko[(((size_t)(b * NH_ + h)) * SK_ + s) * HD_ + d] = val;
                } else {
                    int b = M >> 9, s = M & 511;
                    vo[(((size_t)(b * NH_ + h)) * HD_ + d) * SK_ + s] = val;
                }
            }
        }
    }
}

// ---------------- fused attention (barrier-free) ----------------
// grid B*NH*(SQ/64) = 1024 blocks, 4 waves; wave w owns q-rows [16w,16w+16).
// K/V per head are 64KB each, shared by 32 q-tile blocks -> L2-resident, so
// MFMA fragments are loaded DIRECTLY from global (same logical elements the
// old LDS path produced). Only LDS left: ps (wave-private P relayout, no
// barrier needed) and lm (mask, one barrier at start). Zero per-tile
// syncthreads / vmcnt(0) drains -> deep ILP across the whole 512-k loop.
#define PST 72   // ps stride (shorts): 144B, conflict-free 2-way

__global__ __launch_bounds__(256, 2) void attn_kernel(const unsigned short* __restrict__ qh,
                                                      const unsigned short* __restrict__ kh,
                                                      const unsigned short* __restrict__ vh,
                                                      const int* __restrict__ maskp,
                                                      float* __restrict__ octx,
                                                      float* __restrict__ oscores) {
    __shared__ unsigned short ps[64 * PST];   // P chunk: [qrow][s_local], wave-private rows
    __shared__ float lm[SK_];

    int bid = blockIdx.x;
    bid = (bid & 7) * 128 + (bid >> 3);       // XCD swizzle: 4 whole heads per XCD
    int qt = bid & 31;
    int h  = (bid >> 5) & 15;
    int b  = bid >> 9;

    int tid = threadIdx.x, lane = tid & 63, w = tid >> 6;
    int quad = lane >> 4, lc = lane & 15;
    int wrow = w * 16;

    const unsigned short* qp = qh + ((size_t)(b * NH_ + h) * SQ_ + qt * 64) * HD_;
    const unsigned short* kp = kh + ((size_t)(b * NH_ + h) * SK_) * HD_;
    const unsigned short* vp = vh + ((size_t)(b * NH_ + h) * HD_) * SK_;  // [d][s]

    // stage additive mask (the only cross-wave LDS data -> single barrier)
#pragma unroll
    for (int i = 0; i < 2; i++) {
        int c = tid + i * 256;
        lm[c] = maskp[b * SK_ + c] ? 0.0f : -3.0e38f;
    }
    __syncthreads();

    // Q fragments direct from global: A-frag mirror — lane holds Q[wrow+lc][hf*32+quad*8 ..+8]
    bf16x8 qf[2];
#pragma unroll
    for (int hf = 0; hf < 2; hf++)
        qf[hf] = *reinterpret_cast<const bf16x8*>(qp + (wrow + lc) * 64 + hf * 32 + quad * 8);

    f32x4 zero4 = {0.f, 0.f, 0.f, 0.f};
    f32x4 sacc[32];
#pragma unroll
    for (int t = 0; t < 32; t++) sacc[t] = zero4;

    float* srowp = oscores + ((size_t)(b * NH_ + h) * SQ_ + qt * 64) * SK_;

    // ---- S^T = (K q^T)/8 : K fragments straight from L2, coalesced score stores ----
#pragma unroll
    for (int kt = 0; kt < 8; kt++) {
#pragma unroll
        for (int tl = 0; tl < 4; tl++) {
            int t = kt * 4 + tl;
            const unsigned short* krow = kp + (kt * 64 + tl * 16 + lc) * 64 + quad * 8;
#pragma unroll
            for (int hf = 0; hf < 2; hf++) {
                bf16x8 kf = *reinterpret_cast<const bf16x8*>(krow + hf * 32);
                sacc[t] = __builtin_amdgcn_mfma_f32_16x16x32_bf16(kf, qf[hf], sacc[t], 0, 0, 0);
            }
        }
        // scale + coalesced store: lane holds q-row (wrow+lc), k-cols t*16+quad*4..+3
#pragma unroll
        for (int tl = 0; tl < 4; tl++) {
            int t = kt * 4 + tl;
            sacc[t] *= 0.125f;
            *reinterpret_cast<f32x4*>(&srowp[(size_t)(wrow + lc) * SK_ + t * 16 + quad * 4]) = sacc[t];
        }
    }

    // ---- softmax over 512 k-cols (row replicated across the 4 quads) ----
#pragma unroll
    for (int t = 0; t < 32; t++) {
        float4 mv = *reinterpret_cast<const float4*>(&lm[t * 16 + quad * 4]);
        sacc[t][0] += mv.x; sacc[t][1] += mv.y; sacc[t][2] += mv.z; sacc[t][3] += mv.w;
    }
    float mx = -3.4e38f;
#pragma unroll
    for (int t = 0; t < 32; t++)
#pragma unroll
        for (int j = 0; j < 4; j++) mx = fmaxf(mx, sacc[t][j]);
    mx = fmaxf(mx, __shfl_xor(mx, 16));
    mx = fmaxf(mx, __shfl_xor(mx, 32));
    float sum = 0.f;
#pragma unroll
    for (int t = 0; t < 32; t++)
#pragma unroll
        for (int j = 0; j < 4; j++) {
            float e = __expf(sacc[t][j] - mx);
            sacc[t][j] = e;
            sum += e;
        }
    sum += __shfl_xor(sum, 16);
    sum += __shfl_xor(sum, 32);
    float inv = 1.0f / sum;
#pragma unroll
    for (int t = 0; t < 32; t++) sacc[t] *= inv;

    // ---- context = P @ V  (A=P via wave-private ps relayout, B=V^T from L2) ----
    f32x4 cacc[4];
#pragma unroll
    for (int ct = 0; ct < 4; ct++) cacc[ct] = zero4;

#pragma unroll
    for (int kt = 0; kt < 8; kt++) {
        // write P chunk: lane's 4 probs -> ps[qrow][tl*16+quad*4], wave-private rows,
        // no barrier (same-wave DS ordering + compiler lgkmcnt handle RAW/WAR)
#pragma unroll
        for (int tl = 0; tl < 4; tl++) {
            int t = kt * 4 + tl;
            ushort4 pk;
            pk.x = f2bf(sacc[t][0]); pk.y = f2bf(sacc[t][1]);
            pk.z = f2bf(sacc[t][2]); pk.w = f2bf(sacc[t][3]);
            *reinterpret_cast<ushort4*>(&ps[(wrow + lc) * PST + tl * 16 + quad * 4]) = pk;
        }
#pragma unroll
        for (int ks2 = 0; ks2 < 2; ks2++) {
            bf16x8 af = *reinterpret_cast<const bf16x8*>(&ps[(wrow + lc) * PST + ks2 * 32 + quad * 8]);
#pragma unroll
            for (int ct = 0; ct < 4; ct++) {
                bf16x8 bv = *reinterpret_cast<const bf16x8*>(
                    vp + (size_t)(ct * 16 + lc) * SK_ + kt * 64 + ks2 * 32 + quad * 8);
                cacc[ct] = __builtin_amdgcn_mfma_f32_16x16x32_bf16(af, bv, cacc[ct], 0, 0, 0);
            }
        }
    }

    // context store: [b, s, h*64+d] fp32 (C layout: row=q-in-16, col=d)
#pragma unroll
    for (int ct = 0; ct < 4; ct++) {
        int d = ct * 16 + lc;
#pragma unroll
        for (int r = 0; r < 4; r++) {
            int s = qt * 64 + wrow + quad * 4 + r;
            octx[((size_t)b * SQ_ + s) * HID_ + h * HD_ + d] = cacc[ct][r];
        }
    }
}

// ---------------- launch ----------------
extern "C" void kernel_launch(void* const* d_in, const int* in_sizes, int n_in,
                              void* d_out, int out_size, void* d_ws, size_t ws_size,
                              hipStream_t stream) {
    const float* hs   = (const float*)d_in[0];
    const float* enc  = (const float*)d_in[1];
    const int*   mask = (const int*)d_in[2];
    const float* Wq   = (const float*)d_in[3];
    const float* Wk   = (const float*)d_in[4];
    const float* Wv   = (const float*)d_in[5];
    float* out = (float*)d_out;

    unsigned short* hb  = (unsigned short*)d_ws;      // hidden bf16   (4194304)
    unsigned short* eb  = hb  + 4194304;              // encoder bf16  (1048576)
    unsigned short* wqb = eb  + 1048576;
    unsigned short* wkb = wqb + 1048576;
    unsigned short* wvb = wkb + 1048576;
    unsigned short* qhp = wvb + 1048576;              // q [b,h,s,d]   (4194304)
    unsigned short* khp = qhp + 4194304;              // k [b,h,s,d]   (1048576)
    unsigned short* vhp = khp + 1048576;              // v [b,h,d,s]   (1048576)

    cvt_all<<<8192, 256, 0, stream>>>(hs, enc, Wq, Wk, Wv, hb, eb, wqb, wkb, wvb);
    gemm_qkv<<<384, 256, 0, stream>>>(hb, eb, wqb, wkb, wvb, qhp, khp, vhp);
    attn_kernel<<<1024, 256, 0, stream>>>(qhp, khp, vhp, mask, out, out + 4194304);
}

// Round 2
// 229.705 us; speedup vs baseline: 1.1681x; 1.1681x over previous
//
#include <hip/hip_runtime.h>

#define B_   2
#define SQ_  2048
#define SK_  512
#define HID_ 1024
#define NH_  16
#define HD_  64

typedef __bf16 bf16x8 __attribute__((ext_vector_type(8)));
typedef float  f32x4  __attribute__((ext_vector_type(4)));

__device__ __forceinline__ unsigned short f2bf(float f) {
    unsigned u = __builtin_bit_cast(unsigned, f);
    u += 0x7fffu + ((u >> 16) & 1u);   // round-to-nearest-even
    return (unsigned short)(u >> 16);
}

// async global->LDS, 16B per lane, lands at lds_base + lane*16
__device__ __forceinline__ void gll16(const unsigned short* g, unsigned short* l) {
    __builtin_amdgcn_global_load_lds(
        (const __attribute__((address_space(1))) unsigned int*)(const void*)g,
        (__attribute__((address_space(3))) unsigned int*)(void*)l,
        16, 0, 0);
}

// ---------------- fused fp32 -> bf16 conversion (all 5 tensors) ----------------
__global__ __launch_bounds__(256) void cvt_all(const float* __restrict__ hs,
                                               const float* __restrict__ enc,
                                               const float* __restrict__ wq,
                                               const float* __restrict__ wk,
                                               const float* __restrict__ wv,
                                               unsigned short* __restrict__ hb,
                                               unsigned short* __restrict__ eb,
                                               unsigned short* __restrict__ wqb,
                                               unsigned short* __restrict__ wkb,
                                               unsigned short* __restrict__ wvb) {
    size_t i = ((size_t)blockIdx.x * 256 + threadIdx.x) * 4;
    const float* s; unsigned short* d; size_t off;
    if (i < 4194304)      { s = hs;  d = hb;  off = i; }
    else if (i < 5242880) { s = enc; d = eb;  off = i - 4194304; }
    else if (i < 6291456) { s = wq;  d = wqb; off = i - 5242880; }
    else if (i < 7340032) { s = wk;  d = wkb; off = i - 6291456; }
    else                  { s = wv;  d = wvb; off = i - 7340032; }
    float4 v = *reinterpret_cast<const float4*>(s + off);
    ushort4 o;
    o.x = f2bf(v.x); o.y = f2bf(v.y); o.z = f2bf(v.z); o.w = f2bf(v.w);
    *reinterpret_cast<ushort4*>(d + off) = o;
}

// ---------------- fused QKV NT GEMM ----------------
// 64x128 tiles, BK=32 (verified baseline), now with 2-phase double-buffered
// staging (stage next tile, compute current, ONE barrier per tile) and
// bijective XCD swizzle (768 % 8 == 0; XCD k gets contiguous ms range).
// ms 0..63: Q (A=hb, W=wq) -> qo [b,h,s,d]
// ms 64..79: K (A=eb, W=wk) -> ko [b,h,s,d]
// ms 80..95: V (A=eb, W=wv) -> vo [b,h,d,s]  (pre-transposed for attention)
__global__ __launch_bounds__(256, 4) void gemm_qkv(const unsigned short* __restrict__ hb,
                                                   const unsigned short* __restrict__ eb,
                                                   const unsigned short* __restrict__ wq,
                                                   const unsigned short* __restrict__ wk,
                                                   const unsigned short* __restrict__ wv,
                                                   unsigned short* __restrict__ qo,
                                                   unsigned short* __restrict__ ko,
                                                   unsigned short* __restrict__ vo) {
    __shared__ unsigned short as[2][64 * 32];    // [buf][row][32 k], swizzled chunks
    __shared__ unsigned short bs[2][128 * 32];

    int bid = blockIdx.x;
    bid = (bid & 7) * 96 + (bid >> 3);        // XCD swizzle: 12 ms-superblocks per XCD
    int nb = bid & 7, ms = bid >> 3;
    const unsigned short* Ab; const unsigned short* Wb;
    int mrow, mode;
    if (ms < 64)      { mode = 0; Ab = hb; Wb = wq; mrow = ms * 64; }
    else if (ms < 80) { mode = 1; Ab = eb; Wb = wk; mrow = (ms - 64) * 64; }
    else              { mode = 2; Ab = eb; Wb = wv; mrow = (ms - 80) * 64; }
    int n0 = nb * 128;

    int tid = threadIdx.x, lane = tid & 63, w = tid >> 6;
    int quad = lane >> 4, lc = lane & 15;

    // loader lane mapping: row-in-16 = lane>>2, slot = lane&3, fetched logical chunk = slot ^ ((lane>>3)&3)
    int lrow = lane >> 2;
    int chA  = (lane & 3) ^ ((lane >> 3) & 3);
    const unsigned short* agp  = Ab + (size_t)(mrow + w * 16 + lrow) * 1024 + chA * 8;
    const unsigned short* bgp0 = Wb + (size_t)(n0 + w * 32 + lrow) * 1024 + chA * 8;
    const unsigned short* bgp1 = bgp0 + (size_t)16 * 1024;

    f32x4 zero4 = {0.f, 0.f, 0.f, 0.f};
    f32x4 acc[4][2];
#pragma unroll
    for (int i = 0; i < 4; i++) { acc[i][0] = zero4; acc[i][1] = zero4; }

    int rsw = (lc >> 1) & 3;   // reader swizzle

    // prologue: stage k-tile 0 into buf 0
    gll16(agp,  &as[0][(w * 16) * 32]);
    gll16(bgp0, &bs[0][(w * 32) * 32]);
    gll16(bgp1, &bs[0][(w * 32 + 16) * 32]);
    __syncthreads();

#pragma unroll 2
    for (int it = 0; it < 32; ++it) {
        int cur = it & 1;
        if (it < 31) {                        // issue next-tile stage BEFORE compute
            int k0n = (it + 1) * 32;
            gll16(agp + k0n,  &as[cur ^ 1][(w * 16) * 32]);
            gll16(bgp0 + k0n, &bs[cur ^ 1][(w * 32) * 32]);
            gll16(bgp1 + k0n, &bs[cur ^ 1][(w * 32 + 16) * 32]);
        }
        bf16x8 af[4], bfr[2];
#pragma unroll
        for (int mt = 0; mt < 4; mt++)
            af[mt] = *reinterpret_cast<const bf16x8*>(&as[cur][(mt * 16 + lc) * 32 + (quad ^ rsw) * 8]);
#pragma unroll
        for (int nt = 0; nt < 2; nt++)
            bfr[nt] = *reinterpret_cast<const bf16x8*>(&bs[cur][(w * 32 + nt * 16 + lc) * 32 + (quad ^ rsw) * 8]);
#pragma unroll
        for (int mt = 0; mt < 4; mt++)
#pragma unroll
            for (int nt = 0; nt < 2; nt++)
                acc[mt][nt] = __builtin_amdgcn_mfma_f32_16x16x32_bf16(af[mt], bfr[nt], acc[mt][nt], 0, 0, 0);
        __syncthreads();                      // one barrier per tile: next buf ready + WAR safe
    }

#pragma unroll
    for (int mt = 0; mt < 4; mt++) {
#pragma unroll
        for (int nt = 0; nt < 2; nt++) {
            int n = n0 + w * 32 + nt * 16 + lc;
            int h = n >> 6, d = n & 63;
#pragma unroll
            for (int r = 0; r < 4; r++) {
                int M = mrow + mt * 16 + quad * 4 + r;
                unsigned short val = f2bf(acc[mt][nt][r]);
                if (mode == 0) {
                    int b = M >> 11, s = M & 2047;
                    qo[(((size_t)(b * NH_ + h)) * SQ_ + s) * HD_ + d] = val;
                } else if (mode == 1) {
                    int b = M >> 9, s = M & 511;
                    ko[(((size_t)(b * NH_ + h)) * SK_ + s) * HD_ + d] = val;
                } else {
                    int b = M >> 9, s = M & 511;
                    vo[(((size_t)(b * NH_ + h)) * HD_ + d) * SK_ + s] = val;
                }
            }
        }
    }
}

// ---------------- fused attention ----------------
// grid B*NH*(SQ/64) = 1024 blocks, 4 waves; wave w owns q-rows [16w,16w+16).
// Verified baseline structure (LDS-staged K/V, S^T via A=K B=Q), now with:
//  - double-buffered ks/vts: ONE barrier per tile (was 2), stage overlaps MFMA
//  - score stores hoisted out of the S^T loop (drain off the barrier path,
//    latency hidden under softmax)
//  - V tile 0 staged before softmax (softmax VALU hides HBM latency)
//  - XCD swizzle: 4 whole heads per XCD -> K/V L2 locality
#define PST 72   // ps stride (shorts): 144B, conflict-free 2-way

__global__ __launch_bounds__(256, 2) void attn_kernel(const unsigned short* __restrict__ qh,
                                                      const unsigned short* __restrict__ kh,
                                                      const unsigned short* __restrict__ vh,
                                                      const int* __restrict__ maskp,
                                                      float* __restrict__ octx,
                                                      float* __restrict__ oscores) {
    __shared__ unsigned short qs[64 * 64];
    __shared__ unsigned short ks[2][64 * 64];   // K tile double buffer
    __shared__ unsigned short vts[2][64 * 64];  // V^T tile double buffer: [d][s_local]
    __shared__ unsigned short ps[64 * PST];     // P chunk: [qrow][s_local], wave-private rows
    __shared__ float lm[SK_];

    int bid = blockIdx.x;
    bid = (bid & 7) * 128 + (bid >> 3);         // XCD swizzle: 4 whole heads per XCD
    int qt = bid & 31;
    int h  = (bid >> 5) & 15;
    int b  = bid >> 9;

    int tid = threadIdx.x, lane = tid & 63, w = tid >> 6;
    int quad = lane >> 4, lc = lane & 15;
    int wrow = w * 16;

    const unsigned short* qp = qh + ((size_t)(b * NH_ + h) * SQ_ + qt * 64) * HD_;
    const unsigned short* kp = kh + ((size_t)(b * NH_ + h) * SK_) * HD_;
    const unsigned short* vp = vh + ((size_t)(b * NH_ + h) * HD_) * SK_;  // [d][s]

    // loader mapping for 128B-row tiles: row-in-8 = lane>>3, slot = lane&7,
    // fetched logical chunk = slot ^ (lane>>3)
    int lr  = lane >> 3;
    int chg = (lane & 7) ^ lr;

    // stage q tile + k tile 0 + mask, single barrier
#pragma unroll
    for (int j = 0; j < 2; j++) {
        int c = w * 2 + j;
        gll16(qp + (c * 8 + lr) * 64 + chg * 8, &qs[c * 512]);
        gll16(kp + (c * 8 + lr) * 64 + chg * 8, &ks[0][c * 512]);
    }
#pragma unroll
    for (int i = 0; i < 2; i++) {
        int c = tid + i * 256;
        lm[c] = maskp[b * SK_ + c] ? 0.0f : -3.0e38f;
    }
    __syncthreads();

    int rsw = lc & 7;   // reader swizzle for 8-chunk rows
    bf16x8 qf[2];
#pragma unroll
    for (int hf = 0; hf < 2; hf++)
        qf[hf] = *reinterpret_cast<const bf16x8*>(&qs[(wrow + lc) * 64 + ((quad + hf * 4) ^ rsw) * 8]);

    f32x4 zero4 = {0.f, 0.f, 0.f, 0.f};
    f32x4 sacc[32];
#pragma unroll
    for (int t = 0; t < 32; t++) sacc[t] = zero4;

    // ---- S^T = (K q^T) : 2-phase pipeline, one barrier per K tile ----
#pragma unroll
    for (int kt = 0; kt < 8; kt++) {
        const unsigned short* kcur = ks[kt & 1];
        if (kt < 7) {
            unsigned short* knxt = ks[(kt + 1) & 1];
#pragma unroll
            for (int j = 0; j < 2; j++) {
                int c = w * 2 + j;
                gll16(kp + ((kt + 1) * 64 + c * 8 + lr) * 64 + chg * 8, &knxt[c * 512]);
            }
        }
#pragma unroll
        for (int tl = 0; tl < 4; tl++) {
            int t = kt * 4 + tl;
#pragma unroll
            for (int hf = 0; hf < 2; hf++) {
                bf16x8 kf = *reinterpret_cast<const bf16x8*>(
                    &kcur[(tl * 16 + lc) * 64 + ((quad + hf * 4) ^ rsw) * 8]);
                sacc[t] = __builtin_amdgcn_mfma_f32_16x16x32_bf16(kf, qf[hf], sacc[t], 0, 0, 0);
            }
        }
        __syncthreads();
    }

    // ---- scale + score stores (out of the barrier loop; latency hides under softmax) ----
    float* srowp = oscores + ((size_t)(b * NH_ + h) * SQ_ + qt * 64) * SK_;
#pragma unroll
    for (int t = 0; t < 32; t++) {
        sacc[t] *= 0.125f;
        *reinterpret_cast<f32x4*>(&srowp[(size_t)(wrow + lc) * SK_ + t * 16 + quad * 4]) = sacc[t];
    }

    // issue V tile 0 stage now; softmax VALU hides the HBM/L2 latency
#pragma unroll
    for (int j = 0; j < 2; j++) {
        int c = w * 2 + j;
        gll16(vp + (size_t)(c * 8 + lr) * SK_ + chg * 8, &vts[0][c * 512]);
    }

    // ---- softmax over 512 k-cols (row replicated across the 4 quads) ----
#pragma unroll
    for (int t = 0; t < 32; t++) {
        float4 mv = *reinterpret_cast<const float4*>(&lm[t * 16 + quad * 4]);
        sacc[t][0] += mv.x; sacc[t][1] += mv.y; sacc[t][2] += mv.z; sacc[t][3] += mv.w;
    }
    float mx = -3.4e38f;
#pragma unroll
    for (int t = 0; t < 32; t++)
#pragma unroll
        for (int j = 0; j < 4; j++) mx = fmaxf(mx, sacc[t][j]);
    mx = fmaxf(mx, __shfl_xor(mx, 16));
    mx = fmaxf(mx, __shfl_xor(mx, 32));
    float sum = 0.f;
#pragma unroll
    for (int t = 0; t < 32; t++)
#pragma unroll
        for (int j = 0; j < 4; j++) {
            float e = __expf(sacc[t][j] - mx);
            sacc[t][j] = e;
            sum += e;
        }
    sum += __shfl_xor(sum, 16);
    sum += __shfl_xor(sum, 32);
    float inv = 1.0f / sum;
#pragma unroll
    for (int t = 0; t < 32; t++) sacc[t] *= inv;

    __syncthreads();   // vts[0] staged (vmcnt drained) for all waves

    // ---- context = P @ V : 2-phase pipeline, one barrier per V tile ----
    f32x4 cacc[4];
#pragma unroll
    for (int ct = 0; ct < 4; ct++) cacc[ct] = zero4;

#pragma unroll
    for (int kt = 0; kt < 8; kt++) {
        const unsigned short* vcur = vts[kt & 1];
        if (kt < 7) {
            unsigned short* vnxt = vts[(kt + 1) & 1];
#pragma unroll
            for (int j = 0; j < 2; j++) {
                int c = w * 2 + j;
                gll16(vp + (size_t)(c * 8 + lr) * SK_ + (kt + 1) * 64 + chg * 8, &vnxt[c * 512]);
            }
        }
        // write P chunk: lane's 4 probs -> ps[qrow][tl*16+quad*4]; rows are
        // wave-private (read back by the same wave) -> same-wave lgkmcnt
        // ordering suffices, no barrier between write and read
#pragma unroll
        for (int tl = 0; tl < 4; tl++) {
            int t = kt * 4 + tl;
            ushort4 pk;
            pk.x = f2bf(sacc[t][0]); pk.y = f2bf(sacc[t][1]);
            pk.z = f2bf(sacc[t][2]); pk.w = f2bf(sacc[t][3]);
            *reinterpret_cast<ushort4*>(&ps[(wrow + lc) * PST + tl * 16 + quad * 4]) = pk;
        }
#pragma unroll
        for (int ks2 = 0; ks2 < 2; ks2++) {
            bf16x8 af = *reinterpret_cast<const bf16x8*>(&ps[(wrow + lc) * PST + ks2 * 32 + quad * 8]);
#pragma unroll
            for (int ct = 0; ct < 4; ct++) {
                bf16x8 bv = *reinterpret_cast<const bf16x8*>(
                    &vcur[(ct * 16 + lc) * 64 + ((quad + ks2 * 4) ^ rsw) * 8]);
                cacc[ct] = __builtin_amdgcn_mfma_f32_16x16x32_bf16(af, bv, cacc[ct], 0, 0, 0);
            }
        }
        __syncthreads();
    }

    // context store: [b, s, h*64+d] fp32 (C layout: row=q-in-16, col=d)
#pragma unroll
    for (int ct = 0; ct < 4; ct++) {
        int d = ct * 16 + lc;
#pragma unroll
        for (int r = 0; r < 4; r++) {
            int s = qt * 64 + wrow + quad * 4 + r;
            octx[((size_t)b * SQ_ + s) * HID_ + h * HD_ + d] = cacc[ct][r];
        }
    }
}

// ---------------- launch ----------------
extern "C" void kernel_launch(void* const* d_in, const int* in_sizes, int n_in,
                              void* d_out, int out_size, void* d_ws, size_t ws_size,
                              hipStream_t stream) {
    const float* hs   = (const float*)d_in[0];
    const float* enc  = (const float*)d_in[1];
    const int*   mask = (const int*)d_in[2];
    const float* Wq   = (const float*)d_in[3];
    const float* Wk   = (const float*)d_in[4];
    const float* Wv   = (const float*)d_in[5];
    float* out = (float*)d_out;

    unsigned short* hb  = (unsigned short*)d_ws;      // hidden bf16   (4194304)
    unsigned short* eb  = hb  + 4194304;              // encoder bf16  (1048576)
    unsigned short* wqb = eb  + 1048576;
    unsigned short* wkb = wqb + 1048576;
    unsigned short* wvb = wkb + 1048576;
    unsigned short* qhp = wvb + 1048576;              // q [b,h,s,d]   (4194304)
    unsigned short* khp = qhp + 4194304;              // k [b,h,s,d]   (1048576)
    unsigned short* vhp = khp + 1048576;              // v [b,h,d,s]   (1048576)

    cvt_all<<<8192, 256, 0, stream>>>(hs, enc, Wq, Wk, Wv, hb, eb, wqb, wkb, wvb);
    gemm_qkv<<<768, 256, 0, stream>>>(hb, eb, wqb, wkb, wvb, qhp, khp, vhp);
    attn_kernel<<<1024, 256, 0, stream>>>(qhp, khp, vhp, mask, out, out + 4194304);
}

// Round 3
// 227.385 us; speedup vs baseline: 1.1800x; 1.0102x over previous
//
#include <hip/hip_runtime.h>

#define B_   2
#define SQ_  2048
#define SK_  512
#define HID_ 1024
#define NH_  16
#define HD_  64

typedef __bf16 bf16x8 __attribute__((ext_vector_type(8)));
typedef float  f32x4  __attribute__((ext_vector_type(4)));

__device__ __forceinline__ unsigned short f2bf(float f) {
    unsigned u = __builtin_bit_cast(unsigned, f);
    u += 0x7fffu + ((u >> 16) & 1u);   // round-to-nearest-even
    return (unsigned short)(u >> 16);
}

// async global->LDS, 16B per lane, lands at lds_base + lane*16
__device__ __forceinline__ void gll16(const unsigned short* g, unsigned short* l) {
    __builtin_amdgcn_global_load_lds(
        (const __attribute__((address_space(1))) unsigned int*)(const void*)g,
        (__attribute__((address_space(3))) unsigned int*)(void*)l,
        16, 0, 0);
}

// ---------------- fused fp32 -> bf16 conversion (all 5 tensors) ----------------
__global__ __launch_bounds__(256) void cvt_all(const float* __restrict__ hs,
                                               const float* __restrict__ enc,
                                               const float* __restrict__ wq,
                                               const float* __restrict__ wk,
                                               const float* __restrict__ wv,
                                               unsigned short* __restrict__ hb,
                                               unsigned short* __restrict__ eb,
                                               unsigned short* __restrict__ wqb,
                                               unsigned short* __restrict__ wkb,
                                               unsigned short* __restrict__ wvb) {
    size_t i = ((size_t)blockIdx.x * 256 + threadIdx.x) * 4;
    const float* s; unsigned short* d; size_t off;
    if (i < 4194304)      { s = hs;  d = hb;  off = i; }
    else if (i < 5242880) { s = enc; d = eb;  off = i - 4194304; }
    else if (i < 6291456) { s = wq;  d = wqb; off = i - 5242880; }
    else if (i < 7340032) { s = wk;  d = wkb; off = i - 6291456; }
    else                  { s = wv;  d = wvb; off = i - 7340032; }
    float4 v = *reinterpret_cast<const float4*>(s + off);
    ushort4 o;
    o.x = f2bf(v.x); o.y = f2bf(v.y); o.z = f2bf(v.z); o.w = f2bf(v.w);
    *reinterpret_cast<ushort4*>(d + off) = o;
}

// ---------------- fused QKV NT GEMM ----------------
// 64x128 tiles, BK=64 (this round's single variable: 16 MFMA + 12 ds_read per
// barrier instead of 8+6), double-buffered, one barrier per K-step.
// LDS 48KB -> 3 blocks/CU. 128B-row XOR-chunk swizzle (8 chunks/row).
// grid 768 = 96 m-superblocks x 8 n-blocks, bijective XCD swizzle.
// ms 0..63: Q (A=hb, W=wq) -> qo [b,h,s,d]
// ms 64..79: K (A=eb, W=wk) -> ko [b,h,s,d]
// ms 80..95: V (A=eb, W=wv) -> vo [b,h,d,s]  (pre-transposed for attention)
__global__ __launch_bounds__(256, 3) void gemm_qkv(const unsigned short* __restrict__ hb,
                                                   const unsigned short* __restrict__ eb,
                                                   const unsigned short* __restrict__ wq,
                                                   const unsigned short* __restrict__ wk,
                                                   const unsigned short* __restrict__ wv,
                                                   unsigned short* __restrict__ qo,
                                                   unsigned short* __restrict__ ko,
                                                   unsigned short* __restrict__ vo) {
    __shared__ unsigned short as[2][64 * 64];     // [buf][row][64 k], 128B rows, swizzled chunks
    __shared__ unsigned short bs[2][128 * 64];

    int bid = blockIdx.x;
    bid = (bid & 7) * 96 + (bid >> 3);        // XCD swizzle: 12 ms-superblocks per XCD
    int nb = bid & 7, ms = bid >> 3;
    const unsigned short* Ab; const unsigned short* Wb;
    int mrow, mode;
    if (ms < 64)      { mode = 0; Ab = hb; Wb = wq; mrow = ms * 64; }
    else if (ms < 80) { mode = 1; Ab = eb; Wb = wk; mrow = (ms - 64) * 64; }
    else              { mode = 2; Ab = eb; Wb = wv; mrow = (ms - 80) * 64; }
    int n0 = nb * 128;

    int tid = threadIdx.x, lane = tid & 63, w = tid >> 6;
    int quad = lane >> 4, lc = lane & 15;

    // loader mapping for 128B rows: row-in-8 = lane>>3, slot = lane&7,
    // fetched logical chunk = slot ^ (lane>>3)  => LDS[row][slot] holds chunk slot^(row&7)
    int lr  = lane >> 3;
    int chg = (lane & 7) ^ lr;

    f32x4 zero4 = {0.f, 0.f, 0.f, 0.f};
    f32x4 acc[4][2];
#pragma unroll
    for (int i = 0; i < 4; i++) { acc[i][0] = zero4; acc[i][1] = zero4; }

    int rsw = lc & 7;   // reader swizzle: slot = chunk ^ (row&7), row&7 == lc&7

    // prologue: stage k-tile 0 into buf 0
#pragma unroll
    for (int j = 0; j < 2; j++) {
        int c = w * 2 + j;   // A: 8 rows per gll16, 64 rows total
        gll16(Ab + (size_t)(mrow + c * 8 + lr) * 1024 + chg * 8, &as[0][(c * 8) * 64]);
    }
#pragma unroll
    for (int j = 0; j < 4; j++) {
        int c = w * 4 + j;   // B: 128 rows total
        gll16(Wb + (size_t)(n0 + c * 8 + lr) * 1024 + chg * 8, &bs[0][(c * 8) * 64]);
    }
    __syncthreads();

#pragma unroll 2
    for (int it = 0; it < 16; ++it) {
        int cur = it & 1;
        if (it < 15) {                        // issue next-tile stage BEFORE compute
            int k0n = (it + 1) * 64;
#pragma unroll
            for (int j = 0; j < 2; j++) {
                int c = w * 2 + j;
                gll16(Ab + (size_t)(mrow + c * 8 + lr) * 1024 + k0n + chg * 8,
                      &as[cur ^ 1][(c * 8) * 64]);
            }
#pragma unroll
            for (int j = 0; j < 4; j++) {
                int c = w * 4 + j;
                gll16(Wb + (size_t)(n0 + c * 8 + lr) * 1024 + k0n + chg * 8,
                      &bs[cur ^ 1][(c * 8) * 64]);
            }
        }
#pragma unroll
        for (int kk = 0; kk < 2; kk++) {      // two K=32 halves of the 64-wide tile
            bf16x8 af[4], bfr[2];
#pragma unroll
            for (int mt = 0; mt < 4; mt++)
                af[mt] = *reinterpret_cast<const bf16x8*>(
                    &as[cur][(mt * 16 + lc) * 64 + ((kk * 4 + quad) ^ rsw) * 8]);
#pragma unroll
            for (int nt = 0; nt < 2; nt++)
                bfr[nt] = *reinterpret_cast<const bf16x8*>(
                    &bs[cur][(w * 32 + nt * 16 + lc) * 64 + ((kk * 4 + quad) ^ rsw) * 8]);
#pragma unroll
            for (int mt = 0; mt < 4; mt++)
#pragma unroll
                for (int nt = 0; nt < 2; nt++)
                    acc[mt][nt] = __builtin_amdgcn_mfma_f32_16x16x32_bf16(af[mt], bfr[nt], acc[mt][nt], 0, 0, 0);
        }
        __syncthreads();                      // one barrier per K-step
    }

#pragma unroll
    for (int mt = 0; mt < 4; mt++) {
#pragma unroll
        for (int nt = 0; nt < 2; nt++) {
            int n = n0 + w * 32 + nt * 16 + lc;
            int h = n >> 6, d = n & 63;
#pragma unroll
            for (int r = 0; r < 4; r++) {
                int M = mrow + mt * 16 + quad * 4 + r;
                unsigned short val = f2bf(acc[mt][nt][r]);
                if (mode == 0) {
                    int b = M >> 11, s = M & 2047;
                    qo[(((size_t)(b * NH_ + h)) * SQ_ + s) * HD_ + d] = val;
                } else if (mode == 1) {
                    int b = M >> 9, s = M & 511;
                    ko[(((size_t)(b * NH_ + h)) * SK_ + s) * HD_ + d] = val;
                } else {
                    int b = M >> 9, s = M & 511;
                    vo[(((size_t)(b * NH_ + h)) * HD_ + d) * SK_ + s] = val;
                }
            }
        }
    }
}

// ---------------- fused attention (UNCHANGED from round 2 — control) ----------------
#define PST 72   // ps stride (shorts): 144B, conflict-free 2-way

__global__ __launch_bounds__(256, 2) void attn_kernel(const unsigned short* __restrict__ qh,
                                                      const unsigned short* __restrict__ kh,
                                                      const unsigned short* __restrict__ vh,
                                                      const int* __restrict__ maskp,
                                                      float* __restrict__ octx,
                                                      float* __restrict__ oscores) {
    __shared__ unsigned short qs[64 * 64];
    __shared__ unsigned short ks[2][64 * 64];   // K tile double buffer
    __shared__ unsigned short vts[2][64 * 64];  // V^T tile double buffer: [d][s_local]
    __shared__ unsigned short ps[64 * PST];     // P chunk: [qrow][s_local], wave-private rows
    __shared__ float lm[SK_];

    int bid = blockIdx.x;
    bid = (bid & 7) * 128 + (bid >> 3);         // XCD swizzle: 4 whole heads per XCD
    int qt = bid & 31;
    int h  = (bid >> 5) & 15;
    int b  = bid >> 9;

    int tid = threadIdx.x, lane = tid & 63, w = tid >> 6;
    int quad = lane >> 4, lc = lane & 15;
    int wrow = w * 16;

    const unsigned short* qp = qh + ((size_t)(b * NH_ + h) * SQ_ + qt * 64) * HD_;
    const unsigned short* kp = kh + ((size_t)(b * NH_ + h) * SK_) * HD_;
    const unsigned short* vp = vh + ((size_t)(b * NH_ + h) * HD_) * SK_;  // [d][s]

    // loader mapping for 128B-row tiles: row-in-8 = lane>>3, slot = lane&7,
    // fetched logical chunk = slot ^ (lane>>3)
    int lr  = lane >> 3;
    int chg = (lane & 7) ^ lr;

    // stage q tile + k tile 0 + mask, single barrier
#pragma unroll
    for (int j = 0; j < 2; j++) {
        int c = w * 2 + j;
        gll16(qp + (c * 8 + lr) * 64 + chg * 8, &qs[c * 512]);
        gll16(kp + (c * 8 + lr) * 64 + chg * 8, &ks[0][c * 512]);
    }
#pragma unroll
    for (int i = 0; i < 2; i++) {
        int c = tid + i * 256;
        lm[c] = maskp[b * SK_ + c] ? 0.0f : -3.0e38f;
    }
    __syncthreads();

    int rsw = lc & 7;   // reader swizzle for 8-chunk rows
    bf16x8 qf[2];
#pragma unroll
    for (int hf = 0; hf < 2; hf++)
        qf[hf] = *reinterpret_cast<const bf16x8*>(&qs[(wrow + lc) * 64 + ((quad + hf * 4) ^ rsw) * 8]);

    f32x4 zero4 = {0.f, 0.f, 0.f, 0.f};
    f32x4 sacc[32];
#pragma unroll
    for (int t = 0; t < 32; t++) sacc[t] = zero4;

    // ---- S^T = (K q^T) : 2-phase pipeline, one barrier per K tile ----
#pragma unroll
    for (int kt = 0; kt < 8; kt++) {
        const unsigned short* kcur = ks[kt & 1];
        if (kt < 7) {
            unsigned short* knxt = ks[(kt + 1) & 1];
#pragma unroll
            for (int j = 0; j < 2; j++) {
                int c = w * 2 + j;
                gll16(kp + ((kt + 1) * 64 + c * 8 + lr) * 64 + chg * 8, &knxt[c * 512]);
            }
        }
#pragma unroll
        for (int tl = 0; tl < 4; tl++) {
            int t = kt * 4 + tl;
#pragma unroll
            for (int hf = 0; hf < 2; hf++) {
                bf16x8 kf = *reinterpret_cast<const bf16x8*>(
                    &kcur[(tl * 16 + lc) * 64 + ((quad + hf * 4) ^ rsw) * 8]);
                sacc[t] = __builtin_amdgcn_mfma_f32_16x16x32_bf16(kf, qf[hf], sacc[t], 0, 0, 0);
            }
        }
        __syncthreads();
    }

    // ---- scale + score stores (latency hides under softmax) ----
    float* srowp = oscores + ((size_t)(b * NH_ + h) * SQ_ + qt * 64) * SK_;
#pragma unroll
    for (int t = 0; t < 32; t++) {
        sacc[t] *= 0.125f;
        *reinterpret_cast<f32x4*>(&srowp[(size_t)(wrow + lc) * SK_ + t * 16 + quad * 4]) = sacc[t];
    }

    // issue V tile 0 stage now; softmax VALU hides the HBM/L2 latency
#pragma unroll
    for (int j = 0; j < 2; j++) {
        int c = w * 2 + j;
        gll16(vp + (size_t)(c * 8 + lr) * SK_ + chg * 8, &vts[0][c * 512]);
    }

    // ---- softmax over 512 k-cols (row replicated across the 4 quads) ----
#pragma unroll
    for (int t = 0; t < 32; t++) {
        float4 mv = *reinterpret_cast<const float4*>(&lm[t * 16 + quad * 4]);
        sacc[t][0] += mv.x; sacc[t][1] += mv.y; sacc[t][2] += mv.z; sacc[t][3] += mv.w;
    }
    float mx = -3.4e38f;
#pragma unroll
    for (int t = 0; t < 32; t++)
#pragma unroll
        for (int j = 0; j < 4; j++) mx = fmaxf(mx, sacc[t][j]);
    mx = fmaxf(mx, __shfl_xor(mx, 16));
    mx = fmaxf(mx, __shfl_xor(mx, 32));
    float sum = 0.f;
#pragma unroll
    for (int t = 0; t < 32; t++)
#pragma unroll
        for (int j = 0; j < 4; j++) {
            float e = __expf(sacc[t][j] - mx);
            sacc[t][j] = e;
            sum += e;
        }
    sum += __shfl_xor(sum, 16);
    sum += __shfl_xor(sum, 32);
    float inv = 1.0f / sum;
#pragma unroll
    for (int t = 0; t < 32; t++) sacc[t] *= inv;

    __syncthreads();   // vts[0] staged (vmcnt drained) for all waves

    // ---- context = P @ V : 2-phase pipeline, one barrier per V tile ----
    f32x4 cacc[4];
#pragma unroll
    for (int ct = 0; ct < 4; ct++) cacc[ct] = zero4;

#pragma unroll
    for (int kt = 0; kt < 8; kt++) {
        const unsigned short* vcur = vts[kt & 1];
        if (kt < 7) {
            unsigned short* vnxt = vts[(kt + 1) & 1];
#pragma unroll
            for (int j = 0; j < 2; j++) {
                int c = w * 2 + j;
                gll16(vp + (size_t)(c * 8 + lr) * SK_ + (kt + 1) * 64 + chg * 8, &vnxt[c * 512]);
            }
        }
        // write P chunk: wave-private rows, same-wave lgkmcnt ordering suffices
#pragma unroll
        for (int tl = 0; tl < 4; tl++) {
            int t = kt * 4 + tl;
            ushort4 pk;
            pk.x = f2bf(sacc[t][0]); pk.y = f2bf(sacc[t][1]);
            pk.z = f2bf(sacc[t][2]); pk.w = f2bf(sacc[t][3]);
            *reinterpret_cast<ushort4*>(&ps[(wrow + lc) * PST + tl * 16 + quad * 4]) = pk;
        }
#pragma unroll
        for (int ks2 = 0; ks2 < 2; ks2++) {
            bf16x8 af = *reinterpret_cast<const bf16x8*>(&ps[(wrow + lc) * PST + ks2 * 32 + quad * 8]);
#pragma unroll
            for (int ct = 0; ct < 4; ct++) {
                bf16x8 bv = *reinterpret_cast<const bf16x8*>(
                    &vcur[(ct * 16 + lc) * 64 + ((quad + ks2 * 4) ^ rsw) * 8]);
                cacc[ct] = __builtin_amdgcn_mfma_f32_16x16x32_bf16(af, bv, cacc[ct], 0, 0, 0);
            }
        }
        __syncthreads();
    }

    // context store: [b, s, h*64+d] fp32 (C layout: row=q-in-16, col=d)
#pragma unroll
    for (int ct = 0; ct < 4; ct++) {
        int d = ct * 16 + lc;
#pragma unroll
        for (int r = 0; r < 4; r++) {
            int s = qt * 64 + wrow + quad * 4 + r;
            octx[((size_t)b * SQ_ + s) * HID_ + h * HD_ + d] = cacc[ct][r];
        }
    }
}

// ---------------- launch ----------------
extern "C" void kernel_launch(void* const* d_in, const int* in_sizes, int n_in,
                              void* d_out, int out_size, void* d_ws, size_t ws_size,
                              hipStream_t stream) {
    const float* hs   = (const float*)d_in[0];
    const float* enc  = (const float*)d_in[1];
    const int*   mask = (const int*)d_in[2];
    const float* Wq   = (const float*)d_in[3];
    const float* Wk   = (const float*)d_in[4];
    const float* Wv   = (const float*)d_in[5];
    float* out = (float*)d_out;

    unsigned short* hb  = (unsigned short*)d_ws;      // hidden bf16   (4194304)
    unsigned short* eb  = hb  + 4194304;              // encoder bf16  (1048576)
    unsigned short* wqb = eb  + 1048576;
    unsigned short* wkb = wqb + 1048576;
    unsigned short* wvb = wkb + 1048576;
    unsigned short* qhp = wvb + 1048576;              // q [b,h,s,d]   (4194304)
    unsigned short* khp = qhp + 4194304;              // k [b,h,s,d]   (1048576)
    unsigned short* vhp = khp + 1048576;              // v [b,h,d,s]   (1048576)

    cvt_all<<<8192, 256, 0, stream>>>(hs, enc, Wq, Wk, Wv, hb, eb, wqb, wkb, wvb);
    gemm_qkv<<<768, 256, 0, stream>>>(hb, eb, wqb, wkb, wvb, qhp, khp, vhp);
    attn_kernel<<<1024, 256, 0, stream>>>(qhp, khp, vhp, mask, out, out + 4194304);
}